// Round 2
// baseline (218.629 us; speedup 1.0000x reference)
//
#include <hip/hip_runtime.h>
#include <hip/hip_bf16.h>
#include <math.h>

// Problem: B=4, C=256, H=W=64 (N=4096), IC=128. I/O float32.
// R10: flash converted to 32x32x16 MFMA. Swapped S (mfma(K,Q) -> P^T: lane owns
//     q=lane&31, keys (r&3)+8(r>>2)+4h). PV A-frag built by cvt_pk_bf16 pairs +
//     v_permlane32_swap_b32 (each swap yields TWO frag words) — bpermute/cndmask
//     exchange eliminated entirely (LDS pipe freed). glds src strength-reduced
//     to persistent pointers. s_setprio(1) around MFMA clusters. LDS 64KB,
//     2 blocks/CU, 256 thr / 4 waves / q-tile 128 unchanged.
typedef unsigned short ushort_t;
typedef __attribute__((ext_vector_type(8))) short     short8;   // bf16x8 MFMA frag
typedef __attribute__((ext_vector_type(8))) _Float16  half8;    // f16x8 MFMA frag
typedef __attribute__((ext_vector_type(8))) unsigned short ushort8;
typedef __attribute__((ext_vector_type(4))) float     float4v;
typedef __attribute__((ext_vector_type(16))) float    floatx16; // 32x32 acc

__device__ __forceinline__ float b2f(ushort_t u) {
    return __uint_as_float(((unsigned)u) << 16);
}
__device__ __forceinline__ ushort_t f2b(float f) {
    unsigned i = __float_as_uint(f);
    return (ushort_t)((i + 0x7FFFu + ((i >> 16) & 1u)) >> 16);  // RNE
}
__device__ __forceinline__ void split2(float v, ushort_t& h, ushort_t& l) {
    h = f2b(v);
    l = f2b(v - b2f(h));   // combined rel err ~2^-17
}
__device__ __forceinline__ void glds16(const ushort_t* g, ushort_t* l) {
    __builtin_amdgcn_global_load_lds((const __attribute__((address_space(1))) void*)g,
                                     (__attribute__((address_space(3))) void*)l, 16, 0, 0);
}
__device__ __forceinline__ unsigned int pack2bf(float lo, float hi) {
    unsigned int r;
    asm("v_cvt_pk_bf16_f32 %0, %1, %2" : "=v"(r) : "v"(lo), "v"(hi));
    return r;
}
// v_permlane32_swap_b32: a[32+i] <-> b[i]. After: a=[a.lo, b.lo_old], b=[a.hi_old, b.hi]
__device__ __forceinline__ void pl32swap(unsigned int& a, unsigned int& b) {
    asm("v_permlane32_swap_b32 %0, %1" : "+v"(a), "+v"(b));
}

// ---- workspace layout (bytes) ----
#define WTFH_OFF   0            // 192 KB proj weights B-frag hi
#define WTFL_OFF   196608       // 192 KB lo
#define WWBH_OFF   393216       // 64 KB w_w bf16 hi
#define WWBL_OFF   458752       // 64 KB lo
#define BIAS_OFF   524288       // 384 f32
#define STATS_OFF  526336       // 512 f32
#define PROJF_OFF  1048576      // 8 MB fp16 (theta|phi) [b][n][256]
#define GT_OFF     9437184      // 4 MB bf16 g transposed [b][ic][n]
#define OPART_OFF  13631488     // KQ*8 MB f32 partial O; oml after
#define WY_OFF     1048576      // wy bf16 reuses PROJF region (dead after flash)

__global__ void prep_k(const float* __restrict__ dx_w, const float* __restrict__ dy_w,
                       const float* __restrict__ g_w,  const float* __restrict__ dx_b,
                       const float* __restrict__ dy_b, const float* __restrict__ g_b,
                       const float* __restrict__ w_w,
                       ushort_t* __restrict__ wtfh, ushort_t* __restrict__ wtfl,
                       ushort_t* __restrict__ wwbh, ushort_t* __restrict__ wwbl,
                       float* __restrict__ bias) {
    int idx = blockIdx.x * 256 + threadIdx.x;          // 0..98303
    int j = idx & 7, lane = (idx >> 3) & 63, kk = (idx >> 9) & 7, ot = idx >> 12;
    int o = ot * 16 + (lane & 15);
    int c = kk * 32 + ((lane >> 4) * 8) + j;
    float v;
    if (o < 128)      v = dx_w[o * 256 + c];
    else if (o < 256) v = dy_w[(o - 128) * 256 + c];
    else              v = g_w[(o - 256) * 256 + c];
    ushort_t h, l;
    split2(v, h, l);
    wtfh[idx] = h; wtfl[idx] = l;
    if (idx < 32768) {                                 // w_w [256][128]
        split2(w_w[idx], h, l);
        wwbh[idx] = h; wwbl[idx] = l;
    }
    if (idx < 384) {
        bias[idx] = (idx < 128) ? dx_b[idx]
                  : (idx < 256) ? dy_b[idx - 128]
                                : g_b[idx - 256];
    }
}

// ============================================================================
// Kernel 2: projections, 32-row n-tiles (512 blocks). Split-bf16 compute;
// theta/phi stored fp16 single (feeds fp16 S-phase), g stored bf16 into gT.
// ============================================================================
__global__ __launch_bounds__(256) void proj_k(const float* __restrict__ x,
                                              const float* __restrict__ y,
                                              const ushort_t* __restrict__ wtfh,
                                              const ushort_t* __restrict__ wtfl,
                                              const float* __restrict__ bias,
                                              ushort_t* __restrict__ projf,
                                              ushort_t* __restrict__ gT) {
    __shared__ ushort_t xT[2][32 * 256];   // [hi/lo][n][c], 32KB
    int b = blockIdx.y, n0 = blockIdx.x * 32;
    int tid = threadIdx.x;
    int w = tid >> 6, lane = tid & 63;
    int mrow = lane & 15, quad = lane >> 4, koff = quad * 8;
    int half = w & 1, sect = w >> 1;
    int arow = half * 16 + mrow;

    for (int s = 0; s < 2; s++) {
        if (s) __syncthreads();
        const float* src = s ? y : x;
        #pragma unroll
        for (int i = 0; i < 4; i++) {
            int ch = tid + i * 256;
            int c = ch >> 2, off = (ch & 3) * 8;
            const float* p = src + (size_t)(b * 256 + c) * 4096 + n0 + off;
            float4v v0 = *(const float4v*)p;
            float4v v1 = *(const float4v*)(p + 4);
            #pragma unroll
            for (int jj = 0; jj < 4; jj++) {
                ushort_t h, l;
                split2(v0[jj], h, l);
                xT[0][(off + jj) * 256 + c] = h;
                xT[1][(off + jj) * 256 + c] = l;
                split2(v1[jj], h, l);
                xT[0][(off + 4 + jj) * 256 + c] = h;
                xT[1][(off + 4 + jj) * 256 + c] = l;
            }
        }
        __syncthreads();

        short8 fh[8], fl[8];
        #pragma unroll
        for (int kk = 0; kk < 8; kk++) {
            fh[kk] = *(const short8*)&xT[0][arow * 256 + kk * 32 + koff];
            fl[kk] = *(const short8*)&xT[1][arow * 256 + kk * 32 + koff];
        }

        int ot0 = s ? (8 + sect * 8) : (sect * 4);
        int ot1 = s ? (ot0 + 8) : (ot0 + 4);
        for (int ot = ot0; ot < ot1; ot++) {
            float4v acc = {0.f, 0.f, 0.f, 0.f};
            #pragma unroll
            for (int kk = 0; kk < 8; kk++) {
                short8 bh = *(const short8*)(wtfh + (size_t)((ot * 8 + kk) * 64 + lane) * 8);
                short8 bl = *(const short8*)(wtfl + (size_t)((ot * 8 + kk) * 64 + lane) * 8);
                acc = __builtin_amdgcn_mfma_f32_16x16x32_bf16(fh[kk], bh, acc, 0, 0, 0);
                acc = __builtin_amdgcn_mfma_f32_16x16x32_bf16(fh[kk], bl, acc, 0, 0, 0);
                acc = __builtin_amdgcn_mfma_f32_16x16x32_bf16(fl[kk], bh, acc, 0, 0, 0);
            }
            int o = ot * 16 + mrow;                  // C/D: col = lane&15
            float bo = bias[o];
            #pragma unroll
            for (int r = 0; r < 4; r++) {
                int n = n0 + half * 16 + quad * 4 + r;  // C/D: row = quad*4 + reg
                float v = acc[r] + bo;
                if (ot < 16) {
                    _Float16 hf = (_Float16)v;
                    projf[(size_t)(b * 4096 + n) * 256 + o] = *(ushort_t*)&hf;
                } else {
                    gT[(size_t)(b * 128 + (o - 256)) * 4096 + n] = f2b(v);
                }
            }
        }
    }
}

// ============================================================================
// Kernel 3: flash, 256 threads (4 waves x 32 q-rows = q-tile 128), K-split.
// 32x32x16 MFMA throughout. S^T = mfma_32x32x16_f16(A=K, B=Q): lane owns
// q = lane&31, h = lane>>5; reg r holds key (r&3)+8*(r>>2)+4h (+32 per tile).
// Softmax fully in-register: p = exp2(S*log2e - 64*log2e); l = per-lane f32 sum
// (+ one shfl_xor(32) in epilogue). PV A-frag (needs key = 8h+j per 16-key
// group): pack p pairs with v_cvt_pk_bf16_f32, then ONE v_permlane32_swap_b32
// per word-pair yields BOTH frag words:
//   swap(c0,c2): c0 -> [c0.lo|c2.lo] = word0, c2 -> [c0.hi|c2.hi] = word2.
// No bpermute, no Ps buffer. Double-buffered K/V glds staging (pointers
// strength-reduced), 1 barrier/iter. s_setprio(1) around MFMA clusters.
// ============================================================================
__global__ __launch_bounds__(256, 2) void flash_k(const ushort_t* __restrict__ projf,
                                                  const ushort_t* __restrict__ gT,
                                                  float* __restrict__ opart,
                                                  float* __restrict__ oml,
                                                  int kqlog) {
    __shared__ __align__(16) ushort_t KsF[2][8192];  // fp16 K, frag-order, 16KB/buf
    __shared__ __align__(16) ushort_t VsF[2][8192];  // bf16 V, frag-order

    int b = blockIdx.y;
    int kq = blockIdx.x & ((1 << kqlog) - 1);
    int q0 = (blockIdx.x >> kqlog) * 128;
    int iters = 64 >> kqlog;
    int kt0 = kq * iters;
    int tid = threadIdx.x, w = tid >> 6, lane = tid & 63;
    int ln = lane & 31, hh = lane >> 5;

    // staging: 16 chunks of 64x16B per array; wave w owns chunks w, w+4, w+8, w+12.
    // K chunk c = t2*8+kk: lane reads phi[key=kb+32*t2+ln][ic=16*kk+8*hh+j]
    // V chunk c = it*4+g : lane reads gT [ic=32*it+ln][key=kb+16*g+8*hh+j]
    const ushort_t* kSrc[4];
    const ushort_t* vSrc[4];
    {
        int kb0 = kt0 * 64;
        #pragma unroll
        for (int i = 0; i < 4; i++) {
            int c = w + i * 4;
            int t2 = c >> 3, kk = c & 7;
            kSrc[i] = projf + (size_t)(b * 4096 + kb0 + t2 * 32 + ln) * 256 + 128 + kk * 16 + hh * 8;
            int it = c >> 2, g = c & 3;
            vSrc[i] = gT + (size_t)(b * 128 + it * 32 + ln) * 4096 + kb0 + g * 16 + hh * 8;
        }
    }

    // Q B-frags: B[ic=16*kk+8*hh+j][q=q0+32*w+ln]
    half8 qf[8];
    {
        const ushort_t* qp = projf + (size_t)(b * 4096 + q0 + w * 32 + ln) * 256 + hh * 8;
        #pragma unroll
        for (int kk = 0; kk < 8; kk++)
            qf[kk] = *(const half8*)(qp + kk * 16);
    }

    floatx16 oacc[4];
    #pragma unroll
    for (int it = 0; it < 4; it++)
        #pragma unroll
        for (int j = 0; j < 16; j++) oacc[it][j] = 0.f;
    float lsum = 0.f;

    // prologue: stage kt0 into buf 0
    #pragma unroll
    for (int i = 0; i < 4; i++) {
        int c = w + i * 4;
        glds16(kSrc[i], &KsF[0][c * 512]);
        glds16(vSrc[i], &VsF[0][c * 512]);
        kSrc[i] += 64 * 256;
        vSrc[i] += 64;
    }

    for (int kt = kt0; kt < kt0 + iters; kt++) {
        int cur = (kt - kt0) & 1;
        __syncthreads();                             // publishes buf[cur] (vmcnt drain)
        if (kt + 1 < kt0 + iters) {                  // prefetch next into buf[1-cur]
            #pragma unroll
            for (int i = 0; i < 4; i++) {
                int c = w + i * 4;
                glds16(kSrc[i], &KsF[1 - cur][c * 512]);
                glds16(vSrc[i], &VsF[1 - cur][c * 512]);
                kSrc[i] += 64 * 256;
                vSrc[i] += 64;
            }
        }

        #pragma unroll
        for (int t2 = 0; t2 < 2; t2++) {
            // S^T tile: keys 32*t2..+31
            floatx16 sacc;
            #pragma unroll
            for (int j = 0; j < 16; j++) sacc[j] = 0.f;
            __builtin_amdgcn_s_setprio(1);
            #pragma unroll
            for (int kk = 0; kk < 8; kk++) {
                half8 ah = *(const half8*)&KsF[cur][((t2 * 8 + kk) * 64 + lane) * 8];
                sacc = __builtin_amdgcn_mfma_f32_32x32x16_f16(ah, qf[kk], sacc, 0, 0, 0);
            }
            __builtin_amdgcn_s_setprio(0);

            // fixed-shift softmax p = e^(S-64), pack pairs to bf16
            float ps[16];
            #pragma unroll
            for (int r = 0; r < 16; r++)
                ps[r] = __builtin_exp2f(fmaf(sacc[r], 1.44269504f, -92.332481f));
            #pragma unroll
            for (int r = 0; r < 16; r++) lsum += ps[r];
            unsigned int pkw[8];
            #pragma unroll
            for (int c2 = 0; c2 < 8; c2++) pkw[c2] = pack2bf(ps[2 * c2], ps[2 * c2 + 1]);
            // build PV A-frags: G0 (keys t2*32+0..15), G1 (keys t2*32+16..31)
            pl32swap(pkw[0], pkw[2]);
            pl32swap(pkw[1], pkw[3]);
            pl32swap(pkw[4], pkw[6]);
            pl32swap(pkw[5], pkw[7]);
            union { unsigned int u[4]; short8 s8; } fA, fB;
            fA.u[0] = pkw[0]; fA.u[1] = pkw[1]; fA.u[2] = pkw[2]; fA.u[3] = pkw[3];
            fB.u[0] = pkw[4]; fB.u[1] = pkw[5]; fB.u[2] = pkw[6]; fB.u[3] = pkw[7];

            // O += P.V over this tile's 32 keys (2 k-groups of 16)
            __builtin_amdgcn_s_setprio(1);
            #pragma unroll
            for (int it = 0; it < 4; it++) {
                short8 v0 = *(const short8*)&VsF[cur][((it * 4 + t2 * 2) * 64 + lane) * 8];
                short8 v1 = *(const short8*)&VsF[cur][((it * 4 + t2 * 2 + 1) * 64 + lane) * 8];
                oacc[it] = __builtin_amdgcn_mfma_f32_32x32x16_bf16(fA.s8, v0, oacc[it], 0, 0, 0);
                oacc[it] = __builtin_amdgcn_mfma_f32_32x32x16_bf16(fB.s8, v1, oacc[it], 0, 0, 0);
            }
            __builtin_amdgcn_s_setprio(0);
        }
    }

    // epilogue: raw partial O (common exp shift) + l
    {
        int rowBase = b * 4096 + q0 + w * 32 + hh * 4;
        #pragma unroll
        for (int it = 0; it < 4; it++)
            #pragma unroll
            for (int r = 0; r < 16; r++) {
                int qrow = rowBase + (r & 3) + 8 * (r >> 2);
                opart[((size_t)kq * 16384 + qrow) * 128 + it * 32 + ln] = oacc[it][r];
            }
    }
    lsum += __shfl_xor(lsum, 32, 64);                // join h=0/h=1 key halves
    if (lane < 32)
        oml[kq * 16384 + b * 4096 + q0 + w * 32 + lane] = lsum;
}

// ============================================================================
// Kernel 4: wy = w_w . y2^T + w_b with inline merge of KQ partials
// (y2 = (sum O)/(sum l), common scale -> plain sums). 32-col n-tiles.
// ============================================================================
__global__ __launch_bounds__(256) void wy_k(const float* __restrict__ opart,
                                            const float* __restrict__ oml,
                                            const ushort_t* __restrict__ wwbh,
                                            const ushort_t* __restrict__ wwbl,
                                            const float* __restrict__ w_b,
                                            ushort_t* __restrict__ wy, int KQ) {
    int b = blockIdx.y, n0 = blockIdx.x * 32;
    int tid = threadIdx.x, w = tid >> 6, lane = tid & 63;
    int mrow = lane & 15, quad = lane >> 4, koff = quad * 8;
    int half = w & 1, sect = w >> 1;
    int Rn = b * 4096 + n0 + half * 16 + mrow;

    float L = 0.f;
    for (int kq = 0; kq < KQ; kq++) L += oml[kq * 16384 + Rn];
    float invL = 1.f / L;

    short8 bfh[4], bfl[4];
    #pragma unroll
    for (int kk = 0; kk < 4; kk++) {
        float a[8];
        #pragma unroll
        for (int j = 0; j < 8; j++) a[j] = 0.f;
        for (int kq = 0; kq < KQ; kq++) {
            const float* p = opart + ((size_t)kq * 16384 + Rn) * 128 + kk * 32 + koff;
            float4v v0 = *(const float4v*)p;
            float4v v1 = *(const float4v*)(p + 4);
            #pragma unroll
            for (int j = 0; j < 4; j++) { a[j] += v0[j]; a[4 + j] += v1[j]; }
        }
        #pragma unroll
        for (int j = 0; j < 8; j++) {
            ushort_t h, l;
            split2(a[j] * invL, h, l);
            bfh[kk][j] = (short)h; bfl[kk][j] = (short)l;
        }
    }

    int coln = n0 + half * 16 + mrow;
    for (int cot = sect * 8; cot < sect * 8 + 8; cot++) {
        float4v acc = {0.f, 0.f, 0.f, 0.f};
        #pragma unroll
        for (int kk = 0; kk < 4; kk++) {
            size_t woff = (size_t)(cot * 16 + mrow) * 128 + kk * 32 + koff;
            short8 ah = *(const short8*)(wwbh + woff);
            short8 al = *(const short8*)(wwbl + woff);
            acc = __builtin_amdgcn_mfma_f32_16x16x32_bf16(ah, bfh[kk], acc, 0, 0, 0);
            acc = __builtin_amdgcn_mfma_f32_16x16x32_bf16(ah, bfl[kk], acc, 0, 0, 0);
            acc = __builtin_amdgcn_mfma_f32_16x16x32_bf16(al, bfh[kk], acc, 0, 0, 0);
        }
        #pragma unroll
        for (int r = 0; r < 4; r++) {
            int co = cot * 16 + quad * 4 + r;
            wy[(size_t)(b * 256 + co) * 4096 + coln] = f2b(acc[r] + w_b[co]);
        }
    }
}

// ============================================================================
// Kernel 4b: per-channel sum/sumsq over wy. One block per channel.
// ============================================================================
__global__ __launch_bounds__(256) void stats_k(const ushort_t* __restrict__ wy,
                                               float* __restrict__ stats) {
    __shared__ float red[8];
    int co = blockIdx.x, tid = threadIdx.x, w = tid >> 6, lane = tid & 63;
    float s = 0.f, s2 = 0.f;
    #pragma unroll
    for (int i = 0; i < 8; i++) {
        int ch = tid + i * 256;
        int b = ch >> 9, n = (ch & 511) * 8;
        ushort8 v = *(const ushort8*)(wy + (size_t)(b * 256 + co) * 4096 + n);
        #pragma unroll
        for (int j = 0; j < 8; j++) { float f = b2f(v[j]); s += f; s2 += f * f; }
    }
    #pragma unroll
    for (int d = 1; d < 64; d <<= 1) { s += __shfl_xor(s, d, 64); s2 += __shfl_xor(s2, d, 64); }
    if (lane == 0) { red[w] = s; red[4 + w] = s2; }
    __syncthreads();
    if (tid == 0) {
        stats[co]       = red[0] + red[1] + red[2] + red[3];
        stats[256 + co] = red[4] + red[5] + red[6] + red[7];
    }
}

// ============================================================================
// Kernel 5: BN (batch stats, biased var, eps=1e-5) + residual, f32 out.
// ============================================================================
__global__ __launch_bounds__(256) void bn_k(const ushort_t* __restrict__ wy,
                                            const float* __restrict__ x,
                                            const float* __restrict__ gamma,
                                            const float* __restrict__ beta,
                                            const float* __restrict__ stats,
                                            float* __restrict__ out) {
    int idx = (blockIdx.x * 256 + threadIdx.x) * 8;     // B*C*N = 1<<22
    int c = (idx >> 12) & 255;
    const float inv_cnt = 1.f / 16384.f;
    float mean = stats[c] * inv_cnt;
    float var  = stats[256 + c] * inv_cnt - mean * mean;
    float inv  = rsqrtf(var + 1e-5f);
    float scale = gamma[c] * inv;
    float shift = beta[c] - mean * scale;
    ushort8 wv = *(const ushort8*)(wy + idx);
    float4v x0 = *(const float4v*)(x + idx);
    float4v x1 = *(const float4v*)(x + idx + 4);
    float4v o0, o1;
    #pragma unroll
    for (int j = 0; j < 4; j++) {
        o0[j] = b2f(wv[j]) * scale + shift + x0[j];
        o1[j] = b2f(wv[4 + j]) * scale + shift + x1[j];
    }
    *(float4v*)(out + idx) = o0;
    *(float4v*)(out + idx + 4) = o1;
}

extern "C" void kernel_launch(void* const* d_in, const int* in_sizes, int n_in,
                              void* d_out, int out_size, void* d_ws, size_t ws_size,
                              hipStream_t stream) {
    const float* x    = (const float*)d_in[0];
    const float* y    = (const float*)d_in[1];
    const float* g_w  = (const float*)d_in[2];
    const float* g_b  = (const float*)d_in[3];
    const float* dx_w = (const float*)d_in[4];
    const float* dx_b = (const float*)d_in[5];
    const float* dy_w = (const float*)d_in[6];
    const float* dy_b = (const float*)d_in[7];
    const float* w_w  = (const float*)d_in[8];
    const float* w_b  = (const float*)d_in[9];
    const float* bn_g = (const float*)d_in[10];
    const float* bn_b = (const float*)d_in[11];

    char* ws = (char*)d_ws;
    ushort_t* wtfh  = (ushort_t*)(ws + WTFH_OFF);
    ushort_t* wtfl  = (ushort_t*)(ws + WTFL_OFF);
    ushort_t* wwbh  = (ushort_t*)(ws + WWBH_OFF);
    ushort_t* wwbl  = (ushort_t*)(ws + WWBL_OFF);
    float*    bias  = (float*)(ws + BIAS_OFF);
    float*    stats = (float*)(ws + STATS_OFF);
    ushort_t* projf = (ushort_t*)(ws + PROJF_OFF);
    ushort_t* gT    = (ushort_t*)(ws + GT_OFF);
    float*    opart = (float*)(ws + OPART_OFF);
    ushort_t* wy    = (ushort_t*)(ws + WY_OFF);   // reuses projf region
    float*    out   = (float*)d_out;

    // ws-adaptive K-split: KQ=4 -> 512 blocks of 256 thr = 2 blocks/CU.
    int kqlog;
    if      (ws_size >= 13631488u + 4u * (8388608u + 65536u)) kqlog = 2;
    else if (ws_size >= 13631488u + 2u * (8388608u + 65536u)) kqlog = 1;
    else                                                      kqlog = 0;
    int KQ = 1 << kqlog;
    float* oml = (float*)(ws + OPART_OFF + (size_t)KQ * 8388608u);

    prep_k<<<384, 256, 0, stream>>>(dx_w, dy_w, g_w, dx_b, dy_b, g_b, w_w,
                                    wtfh, wtfl, wwbh, wwbl, bias);
    proj_k<<<dim3(128, 4), 256, 0, stream>>>(x, y, wtfh, wtfl, bias, projf, gT);
    flash_k<<<dim3(32 << kqlog, 4), 256, 0, stream>>>(projf, gT, opart, oml, kqlog);
    wy_k<<<dim3(128, 4), 256, 0, stream>>>(opart, oml, wwbh, wwbl, w_b, wy, KQ);
    stats_k<<<256, 256, 0, stream>>>(wy, stats);
    bn_k<<<2048, 256, 0, stream>>>(wy, x, bn_g, bn_b, stats, out);
}

// Round 3
// 217.635 us; speedup vs baseline: 1.0046x; 1.0046x over previous
//
#include <hip/hip_runtime.h>
#include <hip/hip_bf16.h>
#include <math.h>

// Problem: B=4, C=256, H=W=64 (N=4096), IC=128. I/O float32.
// R11: XCD-aware combo-grouped block swizzle for flash_k. All 32 q-blocks that
//     share one (b,kq) K/V stream (512 KB) get linear block ids congruent mod 8
//     -> same XCD -> stream stays in that XCD's private L2 (2 streams/XCD =
//     1 MB << 4 MB) instead of being re-read 32x through L3. Everything else
//     (R10 32x32 MFMA flash, permlane exchange, glds double-buffer) unchanged.
typedef unsigned short ushort_t;
typedef __attribute__((ext_vector_type(8))) short     short8;   // bf16x8 MFMA frag
typedef __attribute__((ext_vector_type(8))) _Float16  half8;    // f16x8 MFMA frag
typedef __attribute__((ext_vector_type(8))) unsigned short ushort8;
typedef __attribute__((ext_vector_type(4))) float     float4v;
typedef __attribute__((ext_vector_type(16))) float    floatx16; // 32x32 acc

__device__ __forceinline__ float b2f(ushort_t u) {
    return __uint_as_float(((unsigned)u) << 16);
}
__device__ __forceinline__ ushort_t f2b(float f) {
    unsigned i = __float_as_uint(f);
    return (ushort_t)((i + 0x7FFFu + ((i >> 16) & 1u)) >> 16);  // RNE
}
__device__ __forceinline__ void split2(float v, ushort_t& h, ushort_t& l) {
    h = f2b(v);
    l = f2b(v - b2f(h));   // combined rel err ~2^-17
}
__device__ __forceinline__ void glds16(const ushort_t* g, ushort_t* l) {
    __builtin_amdgcn_global_load_lds((const __attribute__((address_space(1))) void*)g,
                                     (__attribute__((address_space(3))) void*)l, 16, 0, 0);
}
__device__ __forceinline__ unsigned int pack2bf(float lo, float hi) {
    unsigned int r;
    asm("v_cvt_pk_bf16_f32 %0, %1, %2" : "=v"(r) : "v"(lo), "v"(hi));
    return r;
}
// v_permlane32_swap_b32: a[32+i] <-> b[i]. After: a=[a.lo, b.lo_old], b=[a.hi_old, b.hi]
__device__ __forceinline__ void pl32swap(unsigned int& a, unsigned int& b) {
    asm("v_permlane32_swap_b32 %0, %1" : "+v"(a), "+v"(b));
}

// ---- workspace layout (bytes) ----
#define WTFH_OFF   0            // 192 KB proj weights B-frag hi
#define WTFL_OFF   196608       // 192 KB lo
#define WWBH_OFF   393216       // 64 KB w_w bf16 hi
#define WWBL_OFF   458752       // 64 KB lo
#define BIAS_OFF   524288       // 384 f32
#define STATS_OFF  526336       // 512 f32
#define PROJF_OFF  1048576      // 8 MB fp16 (theta|phi) [b][n][256]
#define GT_OFF     9437184      // 4 MB bf16 g transposed [b][ic][n]
#define OPART_OFF  13631488     // KQ*8 MB f32 partial O; oml after
#define WY_OFF     1048576      // wy bf16 reuses PROJF region (dead after flash)

__global__ void prep_k(const float* __restrict__ dx_w, const float* __restrict__ dy_w,
                       const float* __restrict__ g_w,  const float* __restrict__ dx_b,
                       const float* __restrict__ dy_b, const float* __restrict__ g_b,
                       const float* __restrict__ w_w,
                       ushort_t* __restrict__ wtfh, ushort_t* __restrict__ wtfl,
                       ushort_t* __restrict__ wwbh, ushort_t* __restrict__ wwbl,
                       float* __restrict__ bias) {
    int idx = blockIdx.x * 256 + threadIdx.x;          // 0..98303
    int j = idx & 7, lane = (idx >> 3) & 63, kk = (idx >> 9) & 7, ot = idx >> 12;
    int o = ot * 16 + (lane & 15);
    int c = kk * 32 + ((lane >> 4) * 8) + j;
    float v;
    if (o < 128)      v = dx_w[o * 256 + c];
    else if (o < 256) v = dy_w[(o - 128) * 256 + c];
    else              v = g_w[(o - 256) * 256 + c];
    ushort_t h, l;
    split2(v, h, l);
    wtfh[idx] = h; wtfl[idx] = l;
    if (idx < 32768) {                                 // w_w [256][128]
        split2(w_w[idx], h, l);
        wwbh[idx] = h; wwbl[idx] = l;
    }
    if (idx < 384) {
        bias[idx] = (idx < 128) ? dx_b[idx]
                  : (idx < 256) ? dy_b[idx - 128]
                                : g_b[idx - 256];
    }
}

// ============================================================================
// Kernel 2: projections, 32-row n-tiles (512 blocks). Split-bf16 compute;
// theta/phi stored fp16 single (feeds fp16 S-phase), g stored bf16 into gT.
// ============================================================================
__global__ __launch_bounds__(256) void proj_k(const float* __restrict__ x,
                                              const float* __restrict__ y,
                                              const ushort_t* __restrict__ wtfh,
                                              const ushort_t* __restrict__ wtfl,
                                              const float* __restrict__ bias,
                                              ushort_t* __restrict__ projf,
                                              ushort_t* __restrict__ gT) {
    __shared__ ushort_t xT[2][32 * 256];   // [hi/lo][n][c], 32KB
    int b = blockIdx.y, n0 = blockIdx.x * 32;
    int tid = threadIdx.x;
    int w = tid >> 6, lane = tid & 63;
    int mrow = lane & 15, quad = lane >> 4, koff = quad * 8;
    int half = w & 1, sect = w >> 1;
    int arow = half * 16 + mrow;

    for (int s = 0; s < 2; s++) {
        if (s) __syncthreads();
        const float* src = s ? y : x;
        #pragma unroll
        for (int i = 0; i < 4; i++) {
            int ch = tid + i * 256;
            int c = ch >> 2, off = (ch & 3) * 8;
            const float* p = src + (size_t)(b * 256 + c) * 4096 + n0 + off;
            float4v v0 = *(const float4v*)p;
            float4v v1 = *(const float4v*)(p + 4);
            #pragma unroll
            for (int jj = 0; jj < 4; jj++) {
                ushort_t h, l;
                split2(v0[jj], h, l);
                xT[0][(off + jj) * 256 + c] = h;
                xT[1][(off + jj) * 256 + c] = l;
                split2(v1[jj], h, l);
                xT[0][(off + 4 + jj) * 256 + c] = h;
                xT[1][(off + 4 + jj) * 256 + c] = l;
            }
        }
        __syncthreads();

        short8 fh[8], fl[8];
        #pragma unroll
        for (int kk = 0; kk < 8; kk++) {
            fh[kk] = *(const short8*)&xT[0][arow * 256 + kk * 32 + koff];
            fl[kk] = *(const short8*)&xT[1][arow * 256 + kk * 32 + koff];
        }

        int ot0 = s ? (8 + sect * 8) : (sect * 4);
        int ot1 = s ? (ot0 + 8) : (ot0 + 4);
        for (int ot = ot0; ot < ot1; ot++) {
            float4v acc = {0.f, 0.f, 0.f, 0.f};
            #pragma unroll
            for (int kk = 0; kk < 8; kk++) {
                short8 bh = *(const short8*)(wtfh + (size_t)((ot * 8 + kk) * 64 + lane) * 8);
                short8 bl = *(const short8*)(wtfl + (size_t)((ot * 8 + kk) * 64 + lane) * 8);
                acc = __builtin_amdgcn_mfma_f32_16x16x32_bf16(fh[kk], bh, acc, 0, 0, 0);
                acc = __builtin_amdgcn_mfma_f32_16x16x32_bf16(fh[kk], bl, acc, 0, 0, 0);
                acc = __builtin_amdgcn_mfma_f32_16x16x32_bf16(fl[kk], bh, acc, 0, 0, 0);
            }
            int o = ot * 16 + mrow;                  // C/D: col = lane&15
            float bo = bias[o];
            #pragma unroll
            for (int r = 0; r < 4; r++) {
                int n = n0 + half * 16 + quad * 4 + r;  // C/D: row = quad*4 + reg
                float v = acc[r] + bo;
                if (ot < 16) {
                    _Float16 hf = (_Float16)v;
                    projf[(size_t)(b * 4096 + n) * 256 + o] = *(ushort_t*)&hf;
                } else {
                    gT[(size_t)(b * 128 + (o - 256)) * 4096 + n] = f2b(v);
                }
            }
        }
    }
}

// ============================================================================
// Kernel 3: flash, 256 threads (4 waves x 32 q-rows = q-tile 128), K-split.
// 32x32x16 MFMA, swapped S, permlane exchange (see R10). NEW in R11: 1-D grid
// with XCD-combo swizzle. combo c = (b,kq) indexes a 512 KB K/V stream shared
// by 32 q-blocks; all of them get block ids == same (mod 8) so the default
// round-robin dispatch puts them on ONE XCD and the stream lives in its L2.
//   kqlog=2: 16 combos, 2 per XCD: L = ((stack*32+j)<<3)|xcd, c=stack*8+xcd
//   kqlog=1:  8 combos, 1 per XCD: L = (j<<3)|c
//   kqlog=0:  4 combos, each split across 2 XCDs {c, c+4}
// ============================================================================
__global__ __launch_bounds__(256, 2) void flash_k(const ushort_t* __restrict__ projf,
                                                  const ushort_t* __restrict__ gT,
                                                  float* __restrict__ opart,
                                                  float* __restrict__ oml,
                                                  int kqlog) {
    __shared__ __align__(16) ushort_t KsF[2][8192];  // fp16 K, frag-order, 16KB/buf
    __shared__ __align__(16) ushort_t VsF[2][8192];  // bf16 V, frag-order

    int L = blockIdx.x;
    int xcd = L & 7, t = L >> 3;
    int c, j;
    if (kqlog == 2)      { c = (t >> 5) * 8 + xcd; j = t & 31; }
    else if (kqlog == 1) { c = xcd;                j = t; }
    else                 { c = xcd & 3;            j = t + ((xcd >> 2) << 4); }
    int b  = c >> kqlog;
    int kq = c & ((1 << kqlog) - 1);
    int q0 = j * 128;
    int iters = 64 >> kqlog;
    int kt0 = kq * iters;
    int tid = threadIdx.x, w = tid >> 6, lane = tid & 63;
    int ln = lane & 31, hh = lane >> 5;

    // staging: 16 chunks of 64x16B per array; wave w owns chunks w, w+4, w+8, w+12.
    // K chunk c = t2*8+kk: lane reads phi[key=kb+32*t2+ln][ic=16*kk+8*hh+j]
    // V chunk c = it*4+g : lane reads gT [ic=32*it+ln][key=kb+16*g+8*hh+j]
    const ushort_t* kSrc[4];
    const ushort_t* vSrc[4];
    {
        int kb0 = kt0 * 64;
        #pragma unroll
        for (int i = 0; i < 4; i++) {
            int cc = w + i * 4;
            int t2 = cc >> 3, kk = cc & 7;
            kSrc[i] = projf + (size_t)(b * 4096 + kb0 + t2 * 32 + ln) * 256 + 128 + kk * 16 + hh * 8;
            int it = cc >> 2, g = cc & 3;
            vSrc[i] = gT + (size_t)(b * 128 + it * 32 + ln) * 4096 + kb0 + g * 16 + hh * 8;
        }
    }

    // Q B-frags: B[ic=16*kk+8*hh+j][q=q0+32*w+ln]
    half8 qf[8];
    {
        const ushort_t* qp = projf + (size_t)(b * 4096 + q0 + w * 32 + ln) * 256 + hh * 8;
        #pragma unroll
        for (int kk = 0; kk < 8; kk++)
            qf[kk] = *(const half8*)(qp + kk * 16);
    }

    floatx16 oacc[4];
    #pragma unroll
    for (int it = 0; it < 4; it++)
        #pragma unroll
        for (int jj = 0; jj < 16; jj++) oacc[it][jj] = 0.f;
    float lsum = 0.f;

    // prologue: stage kt0 into buf 0
    #pragma unroll
    for (int i = 0; i < 4; i++) {
        int cc = w + i * 4;
        glds16(kSrc[i], &KsF[0][cc * 512]);
        glds16(vSrc[i], &VsF[0][cc * 512]);
        kSrc[i] += 64 * 256;
        vSrc[i] += 64;
    }

    for (int kt = kt0; kt < kt0 + iters; kt++) {
        int cur = (kt - kt0) & 1;
        __syncthreads();                             // publishes buf[cur] (vmcnt drain)
        if (kt + 1 < kt0 + iters) {                  // prefetch next into buf[1-cur]
            #pragma unroll
            for (int i = 0; i < 4; i++) {
                int cc = w + i * 4;
                glds16(kSrc[i], &KsF[1 - cur][cc * 512]);
                glds16(vSrc[i], &VsF[1 - cur][cc * 512]);
                kSrc[i] += 64 * 256;
                vSrc[i] += 64;
            }
        }

        #pragma unroll
        for (int t2 = 0; t2 < 2; t2++) {
            // S^T tile: keys 32*t2..+31
            floatx16 sacc;
            #pragma unroll
            for (int jj = 0; jj < 16; jj++) sacc[jj] = 0.f;
            __builtin_amdgcn_s_setprio(1);
            #pragma unroll
            for (int kk = 0; kk < 8; kk++) {
                half8 ah = *(const half8*)&KsF[cur][((t2 * 8 + kk) * 64 + lane) * 8];
                sacc = __builtin_amdgcn_mfma_f32_32x32x16_f16(ah, qf[kk], sacc, 0, 0, 0);
            }
            __builtin_amdgcn_s_setprio(0);

            // fixed-shift softmax p = e^(S-64), pack pairs to bf16
            float ps[16];
            #pragma unroll
            for (int r = 0; r < 16; r++)
                ps[r] = __builtin_exp2f(fmaf(sacc[r], 1.44269504f, -92.332481f));
            #pragma unroll
            for (int r = 0; r < 16; r++) lsum += ps[r];
            unsigned int pkw[8];
            #pragma unroll
            for (int c2 = 0; c2 < 8; c2++) pkw[c2] = pack2bf(ps[2 * c2], ps[2 * c2 + 1]);
            // build PV A-frags: G0 (keys t2*32+0..15), G1 (keys t2*32+16..31)
            pl32swap(pkw[0], pkw[2]);
            pl32swap(pkw[1], pkw[3]);
            pl32swap(pkw[4], pkw[6]);
            pl32swap(pkw[5], pkw[7]);
            union { unsigned int u[4]; short8 s8; } fA, fB;
            fA.u[0] = pkw[0]; fA.u[1] = pkw[1]; fA.u[2] = pkw[2]; fA.u[3] = pkw[3];
            fB.u[0] = pkw[4]; fB.u[1] = pkw[5]; fB.u[2] = pkw[6]; fB.u[3] = pkw[7];

            // O += P.V over this tile's 32 keys (2 k-groups of 16)
            __builtin_amdgcn_s_setprio(1);
            #pragma unroll
            for (int it = 0; it < 4; it++) {
                short8 v0 = *(const short8*)&VsF[cur][((it * 4 + t2 * 2) * 64 + lane) * 8];
                short8 v1 = *(const short8*)&VsF[cur][((it * 4 + t2 * 2 + 1) * 64 + lane) * 8];
                oacc[it] = __builtin_amdgcn_mfma_f32_32x32x16_bf16(fA.s8, v0, oacc[it], 0, 0, 0);
                oacc[it] = __builtin_amdgcn_mfma_f32_32x32x16_bf16(fB.s8, v1, oacc[it], 0, 0, 0);
            }
            __builtin_amdgcn_s_setprio(0);
        }
    }

    // epilogue: raw partial O (common exp shift) + l
    {
        int rowBase = b * 4096 + q0 + w * 32 + hh * 4;
        #pragma unroll
        for (int it = 0; it < 4; it++)
            #pragma unroll
            for (int r = 0; r < 16; r++) {
                int qrow = rowBase + (r & 3) + 8 * (r >> 2);
                opart[((size_t)kq * 16384 + qrow) * 128 + it * 32 + ln] = oacc[it][r];
            }
    }
    lsum += __shfl_xor(lsum, 32, 64);                // join h=0/h=1 key halves
    if (lane < 32)
        oml[kq * 16384 + b * 4096 + q0 + w * 32 + lane] = lsum;
}

// ============================================================================
// Kernel 4: wy = w_w . y2^T + w_b with inline merge of KQ partials
// (y2 = (sum O)/(sum l), common scale -> plain sums). 32-col n-tiles.
// ============================================================================
__global__ __launch_bounds__(256) void wy_k(const float* __restrict__ opart,
                                            const float* __restrict__ oml,
                                            const ushort_t* __restrict__ wwbh,
                                            const ushort_t* __restrict__ wwbl,
                                            const float* __restrict__ w_b,
                                            ushort_t* __restrict__ wy, int KQ) {
    int b = blockIdx.y, n0 = blockIdx.x * 32;
    int tid = threadIdx.x, w = tid >> 6, lane = tid & 63;
    int mrow = lane & 15, quad = lane >> 4, koff = quad * 8;
    int half = w & 1, sect = w >> 1;
    int Rn = b * 4096 + n0 + half * 16 + mrow;

    float L = 0.f;
    for (int kq = 0; kq < KQ; kq++) L += oml[kq * 16384 + Rn];
    float invL = 1.f / L;

    short8 bfh[4], bfl[4];
    #pragma unroll
    for (int kk = 0; kk < 4; kk++) {
        float a[8];
        #pragma unroll
        for (int j = 0; j < 8; j++) a[j] = 0.f;
        for (int kq = 0; kq < KQ; kq++) {
            const float* p = opart + ((size_t)kq * 16384 + Rn) * 128 + kk * 32 + koff;
            float4v v0 = *(const float4v*)p;
            float4v v1 = *(const float4v*)(p + 4);
            #pragma unroll
            for (int j = 0; j < 4; j++) { a[j] += v0[j]; a[4 + j] += v1[j]; }
        }
        #pragma unroll
        for (int j = 0; j < 8; j++) {
            ushort_t h, l;
            split2(a[j] * invL, h, l);
            bfh[kk][j] = (short)h; bfl[kk][j] = (short)l;
        }
    }

    int coln = n0 + half * 16 + mrow;
    for (int cot = sect * 8; cot < sect * 8 + 8; cot++) {
        float4v acc = {0.f, 0.f, 0.f, 0.f};
        #pragma unroll
        for (int kk = 0; kk < 4; kk++) {
            size_t woff = (size_t)(cot * 16 + mrow) * 128 + kk * 32 + koff;
            short8 ah = *(const short8*)(wwbh + woff);
            short8 al = *(const short8*)(wwbl + woff);
            acc = __builtin_amdgcn_mfma_f32_16x16x32_bf16(ah, bfh[kk], acc, 0, 0, 0);
            acc = __builtin_amdgcn_mfma_f32_16x16x32_bf16(ah, bfl[kk], acc, 0, 0, 0);
            acc = __builtin_amdgcn_mfma_f32_16x16x32_bf16(al, bfh[kk], acc, 0, 0, 0);
        }
        #pragma unroll
        for (int r = 0; r < 4; r++) {
            int co = cot * 16 + quad * 4 + r;
            wy[(size_t)(b * 256 + co) * 4096 + coln] = f2b(acc[r] + w_b[co]);
        }
    }
}

// ============================================================================
// Kernel 4b: per-channel sum/sumsq over wy. One block per channel.
// ============================================================================
__global__ __launch_bounds__(256) void stats_k(const ushort_t* __restrict__ wy,
                                               float* __restrict__ stats) {
    __shared__ float red[8];
    int co = blockIdx.x, tid = threadIdx.x, w = tid >> 6, lane = tid & 63;
    float s = 0.f, s2 = 0.f;
    #pragma unroll
    for (int i = 0; i < 8; i++) {
        int ch = tid + i * 256;
        int b = ch >> 9, n = (ch & 511) * 8;
        ushort8 v = *(const ushort8*)(wy + (size_t)(b * 256 + co) * 4096 + n);
        #pragma unroll
        for (int j = 0; j < 8; j++) { float f = b2f(v[j]); s += f; s2 += f * f; }
    }
    #pragma unroll
    for (int d = 1; d < 64; d <<= 1) { s += __shfl_xor(s, d, 64); s2 += __shfl_xor(s2, d, 64); }
    if (lane == 0) { red[w] = s; red[4 + w] = s2; }
    __syncthreads();
    if (tid == 0) {
        stats[co]       = red[0] + red[1] + red[2] + red[3];
        stats[256 + co] = red[4] + red[5] + red[6] + red[7];
    }
}

// ============================================================================
// Kernel 5: BN (batch stats, biased var, eps=1e-5) + residual, f32 out.
// ============================================================================
__global__ __launch_bounds__(256) void bn_k(const ushort_t* __restrict__ wy,
                                            const float* __restrict__ x,
                                            const float* __restrict__ gamma,
                                            const float* __restrict__ beta,
                                            const float* __restrict__ stats,
                                            float* __restrict__ out) {
    int idx = (blockIdx.x * 256 + threadIdx.x) * 8;     // B*C*N = 1<<22
    int c = (idx >> 12) & 255;
    const float inv_cnt = 1.f / 16384.f;
    float mean = stats[c] * inv_cnt;
    float var  = stats[256 + c] * inv_cnt - mean * mean;
    float inv  = rsqrtf(var + 1e-5f);
    float scale = gamma[c] * inv;
    float shift = beta[c] - mean * scale;
    ushort8 wv = *(const ushort8*)(wy + idx);
    float4v x0 = *(const float4v*)(x + idx);
    float4v x1 = *(const float4v*)(x + idx + 4);
    float4v o0, o1;
    #pragma unroll
    for (int j = 0; j < 4; j++) {
        o0[j] = b2f(wv[j]) * scale + shift + x0[j];
        o1[j] = b2f(wv[4 + j]) * scale + shift + x1[j];
    }
    *(float4v*)(out + idx) = o0;
    *(float4v*)(out + idx + 4) = o1;
}

extern "C" void kernel_launch(void* const* d_in, const int* in_sizes, int n_in,
                              void* d_out, int out_size, void* d_ws, size_t ws_size,
                              hipStream_t stream) {
    const float* x    = (const float*)d_in[0];
    const float* y    = (const float*)d_in[1];
    const float* g_w  = (const float*)d_in[2];
    const float* g_b  = (const float*)d_in[3];
    const float* dx_w = (const float*)d_in[4];
    const float* dx_b = (const float*)d_in[5];
    const float* dy_w = (const float*)d_in[6];
    const float* dy_b = (const float*)d_in[7];
    const float* w_w  = (const float*)d_in[8];
    const float* w_b  = (const float*)d_in[9];
    const float* bn_g = (const float*)d_in[10];
    const float* bn_b = (const float*)d_in[11];

    char* ws = (char*)d_ws;
    ushort_t* wtfh  = (ushort_t*)(ws + WTFH_OFF);
    ushort_t* wtfl  = (ushort_t*)(ws + WTFL_OFF);
    ushort_t* wwbh  = (ushort_t*)(ws + WWBH_OFF);
    ushort_t* wwbl  = (ushort_t*)(ws + WWBL_OFF);
    float*    bias  = (float*)(ws + BIAS_OFF);
    float*    stats = (float*)(ws + STATS_OFF);
    ushort_t* projf = (ushort_t*)(ws + PROJF_OFF);
    ushort_t* gT    = (ushort_t*)(ws + GT_OFF);
    float*    opart = (float*)(ws + OPART_OFF);
    ushort_t* wy    = (ushort_t*)(ws + WY_OFF);   // reuses projf region
    float*    out   = (float*)d_out;

    // ws-adaptive K-split: KQ=4 -> 512 blocks of 256 thr = 2 blocks/CU.
    int kqlog;
    if      (ws_size >= 13631488u + 4u * (8388608u + 65536u)) kqlog = 2;
    else if (ws_size >= 13631488u + 2u * (8388608u + 65536u)) kqlog = 1;
    else                                                      kqlog = 0;
    int KQ = 1 << kqlog;
    float* oml = (float*)(ws + OPART_OFF + (size_t)KQ * 8388608u);

    prep_k<<<384, 256, 0, stream>>>(dx_w, dy_w, g_w, dx_b, dy_b, g_b, w_w,
                                    wtfh, wtfl, wwbh, wwbl, bias);
    proj_k<<<dim3(128, 4), 256, 0, stream>>>(x, y, wtfh, wtfl, bias, projf, gT);
    flash_k<<<dim3(128 << kqlog), 256, 0, stream>>>(projf, gT, opart, oml, kqlog);
    wy_k<<<dim3(128, 4), 256, 0, stream>>>(opart, oml, wwbh, wwbl, w_b, wy, KQ);
    stats_k<<<256, 256, 0, stream>>>(wy, stats);
    bn_k<<<2048, 256, 0, stream>>>(wy, x, bn_g, bn_b, stats, out);
}